// Round 2
// baseline (645.707 us; speedup 1.0000x reference)
//
#include <hip/hip_runtime.h>

// ---- problem constants ----
#define Bq   4
#define Sq   2048
#define Eq   1024
#define Hq   16
#define HDq  64
#define Mq   (Bq*Sq)       // 8192
#define N1q  (3*Eq)        // 3072
#define Kq   Eq            // 1024

typedef __bf16 bf16x8 __attribute__((ext_vector_type(8)));
typedef __bf16 bf16x4 __attribute__((ext_vector_type(4)));
typedef float  f32x4  __attribute__((ext_vector_type(4)));

#define GAS __attribute__((address_space(1)))
#define LAS __attribute__((address_space(3)))

__device__ __forceinline__ void gl2lds16(const void* g, void* l) {
  // async global->LDS, 16B per lane; LDS dest = wave-uniform base + lane*16
  __builtin_amdgcn_global_load_lds((GAS const void*)g, (LAS void*)l, 16, 0, 0);
}

// ---------------- fp32 -> bf16 convert (float4 vectorized) ----------------
__global__ __launch_bounds__(256) void cvt4(const float* __restrict__ in,
                                            __bf16* __restrict__ out, int n4) {
  int i = blockIdx.x * 256 + threadIdx.x;
  if (i >= n4) return;
  float4 v = ((const float4*)in)[i];
  bf16x4 o = { (__bf16)v.x, (__bf16)v.y, (__bf16)v.z, (__bf16)v.w };
  ((bf16x4*)out)[i] = o;
}

// ---------------- GEMM  C = A(MxK) * B(NxK)^T  (both K-major, bf16) ------
// MODE 0: write bf16 C to qkv_out[m*N+n]
// MODE 1: write fp32 C + bias to out[m*N+n]
template <int MODE>
__global__ __launch_bounds__(256) void gemm_bt(const __bf16* __restrict__ A,
                                               const __bf16* __restrict__ Bw,
                                               int N, int K,
                                               __bf16* __restrict__ cbf,
                                               const float* __restrict__ bias,
                                               float* __restrict__ cf32) {
  __shared__ __align__(16) __bf16 As[128 * 32];
  __shared__ __align__(16) __bf16 Bs[128 * 32];
  const int tid  = threadIdx.x;
  const int wave = tid >> 6, lane = tid & 63;
  const int quad = lane >> 4, l15 = lane & 15;
  const int wm = wave & 1, wn = wave >> 1;       // 2x2 wave grid, 64x64 each
  const int bm0 = blockIdx.x * 128;
  const int bn0 = blockIdx.y * 128;

  f32x4 acc[4][4] = {};

  const int ar = tid >> 2, ac = (tid & 3) * 8;
  const __bf16* Ag0 = A  + (long)(bm0 + ar) * K + ac;
  const __bf16* Bg0 = Bw + (long)(bn0 + ar) * K + ac;
  __bf16* As0 = As + wave * 512; __bf16* As1 = As + 2048 + wave * 512;
  __bf16* Bs0 = Bs + wave * 512; __bf16* Bs1 = Bs + 2048 + wave * 512;

  for (int kc = 0; kc < K; kc += 32) {
    gl2lds16(Ag0 + kc,          As0);
    gl2lds16(Ag0 + 64 * K + kc, As1);
    gl2lds16(Bg0 + kc,          Bs0);
    gl2lds16(Bg0 + 64 * K + kc, Bs1);
    __syncthreads();

    bf16x8 af[4], bfr[4];
#pragma unroll
    for (int mt = 0; mt < 4; mt++)
      af[mt] = *(const bf16x8*)&As[(wm * 64 + mt * 16 + l15) * 32 + quad * 8];
#pragma unroll
    for (int nt = 0; nt < 4; nt++)
      bfr[nt] = *(const bf16x8*)&Bs[(wn * 64 + nt * 16 + l15) * 32 + quad * 8];
#pragma unroll
    for (int mt = 0; mt < 4; mt++)
#pragma unroll
      for (int nt = 0; nt < 4; nt++)
        acc[mt][nt] = __builtin_amdgcn_mfma_f32_16x16x32_bf16(af[mt], bfr[nt], acc[mt][nt], 0, 0, 0);
    __syncthreads();
  }

#pragma unroll
  for (int nt = 0; nt < 4; nt++) {
    const int n = bn0 + wn * 64 + nt * 16 + l15;
    float bv = 0.f;
    if (MODE == 1) bv = bias[n];
#pragma unroll
    for (int mt = 0; mt < 4; mt++) {
      const int mbase = bm0 + wm * 64 + mt * 16 + quad * 4;
#pragma unroll
      for (int r = 0; r < 4; r++) {
        const long m = mbase + r;
        if (MODE == 0) cbf[m * N + n] = (__bf16)acc[mt][nt][r];
        else           cf32[m * N + n] = acc[mt][nt][r] + bv;
      }
    }
  }
}

// ---------------- V transpose: qkv natural layout -> vt[bh][d][s] --------
__global__ __launch_bounds__(256) void transv(const __bf16* __restrict__ qkv,
                                              __bf16* __restrict__ vt) {
  __shared__ __align__(16) __bf16 T[64 * 64];   // [s_local][d]
  const int tid = threadIdx.x, wave = tid >> 6;
  const int bh = blockIdx.x >> 5, st = blockIdx.x & 31;
  const int b = bh >> 4, h = bh & 15;
  const long gbase = (long)(b * Sq + st * 64 + (tid >> 3)) * N1q + h * 192 + 128 + (tid & 7) * 8;
  gl2lds16(qkv + gbase,                 T + wave * 512);
  gl2lds16(qkv + gbase + (long)32 * N1q, T + 2048 + wave * 512);
  __syncthreads();
  const int d = tid >> 2, s4 = (tid & 3) * 16;
  bf16x8 o0, o1;
#pragma unroll
  for (int j = 0; j < 8; j++) o0[j] = T[(s4 + j) * 64 + d];
#pragma unroll
  for (int j = 0; j < 8; j++) o1[j] = T[(s4 + 8 + j) * 64 + d];
  __bf16* dst = vt + (long)(bh * 64 + d) * Sq + st * 64 + s4;
  *(bf16x8*)dst = o0;
  *(bf16x8*)(dst + 8) = o1;
}

// ---------------- flash attention fwd (causal), barrier-free -------------
// block = (b,h,qt): 4 waves x 16 q-rows = 64-row Q tile; K/V tiles of 64.
// K and V fragments load DIRECTLY from global (L1/L2-resident: shared by
// 4 waves x 32 qt-blocks per (b,h)) -> no staging barriers, no Ks/Vs bank
// conflicts. Only LDS use is the per-wave P layout transform (no barrier).
__global__ __launch_bounds__(256, 3) void attn_fwd(const __bf16* __restrict__ qkv,
                                                   const __bf16* __restrict__ vt,
                                                   __bf16* __restrict__ aout) {
  __shared__ __align__(16) __bf16 Ps[4][16 * 72];   // per-wave P, stride 72 (pad)

  const int tid = threadIdx.x;
  const int wave = tid >> 6, lane = tid & 63;
  const int quad = lane >> 4, l15 = lane & 15;
  const int qt = blockIdx.x & 31, bh = blockIdx.x >> 5;
  const int b = bh >> 4, h = bh & 15;
  const int qr0 = qt * 64 + wave * 16;

  // Q fragment (A-layout: m=l15, k=quad*8+j), HD=64 -> 2 chunks of 32
  const long qrow = (long)(b * Sq + qr0 + l15);
  const bf16x8 qf0 = *(const bf16x8*)(qkv + qrow * N1q + h * 192 + quad * 8);
  const bf16x8 qf1 = *(const bf16x8*)(qkv + qrow * N1q + h * 192 + 32 + quad * 8);

  // B-fragment base pointers (lane-resolved): K row l15, col-chunk quad
  const __bf16* Kp = qkv + (long)(b * Sq + l15) * N1q + h * 192 + 64 + quad * 8;
  const __bf16* Vp = vt + (long)(bh * 64 + l15) * Sq + quad * 8;

  f32x4 oacc[4] = {};
  float m_i[4] = {-1e30f, -1e30f, -1e30f, -1e30f};
  float l_i[4] = {};
  constexpr float SC2 = 0.18033688011112042f;   // HD^-0.5 * log2(e)

  for (int kt = 0; kt <= qt; kt++) {
    const __bf16* Kt = Kp + (long)(kt * 64) * N1q;

    // scores S = Q K^T : D[m=qrow][n=kcol]; B-frag n=nt*16+l15 row of K
    f32x4 sc[4];
#pragma unroll
    for (int nt = 0; nt < 4; nt++) {
      bf16x8 k0 = *(const bf16x8*)(Kt + (long)(nt * 16) * N1q);
      bf16x8 k1 = *(const bf16x8*)(Kt + (long)(nt * 16) * N1q + 32);
      f32x4 z = {};
      z = __builtin_amdgcn_mfma_f32_16x16x32_bf16(qf0, k0, z, 0, 0, 0);
      z = __builtin_amdgcn_mfma_f32_16x16x32_bf16(qf1, k1, z, 0, 0, 0);
      sc[nt] = z;
    }

    // prefetch V fragments now; consumed after softmax (latency overlap)
    bf16x8 vb[4][2];
#pragma unroll
    for (int nt = 0; nt < 4; nt++) {
      vb[nt][0] = *(const bf16x8*)(Vp + (long)(nt * 16) * Sq + kt * 64);
      vb[nt][1] = *(const bf16x8*)(Vp + (long)(nt * 16) * Sq + kt * 64 + 32);
    }

    // base-2 online softmax (scale folded with log2e -> single v_exp_f32)
    const bool diag = (kt == qt);
    float mt4[4] = {-1e30f, -1e30f, -1e30f, -1e30f};
#pragma unroll
    for (int nt = 0; nt < 4; nt++)
#pragma unroll
      for (int r = 0; r < 4; r++) {
        float s = sc[nt][r] * SC2;
        if (diag && (kt * 64 + nt * 16 + l15 > qr0 + quad * 4 + r)) s = -1e30f;
        sc[nt][r] = s;
        mt4[r] = fmaxf(mt4[r], s);
      }
#pragma unroll
    for (int off = 8; off; off >>= 1)
#pragma unroll
      for (int r = 0; r < 4; r++) mt4[r] = fmaxf(mt4[r], __shfl_xor(mt4[r], off));

    float alpha[4];
#pragma unroll
    for (int r = 0; r < 4; r++) {
      float mn = fmaxf(m_i[r], mt4[r]);
      alpha[r] = exp2f(m_i[r] - mn);
      m_i[r] = mn;
    }
    float rs[4] = {};
#pragma unroll
    for (int nt = 0; nt < 4; nt++)
#pragma unroll
      for (int r = 0; r < 4; r++) {
        float p = exp2f(sc[nt][r] - m_i[r]);
        sc[nt][r] = p;
        rs[r] += p;
      }
#pragma unroll
    for (int off = 8; off; off >>= 1)
#pragma unroll
      for (int r = 0; r < 4; r++) rs[r] += __shfl_xor(rs[r], off);
#pragma unroll
    for (int r = 0; r < 4; r++) l_i[r] = l_i[r] * alpha[r] + rs[r];
#pragma unroll
    for (int nt = 0; nt < 4; nt++)
#pragma unroll
      for (int r = 0; r < 4; r++) oacc[nt][r] *= alpha[r];

    // P: C-layout -> LDS -> A-layout (per-wave region, no barrier needed)
#pragma unroll
    for (int nt = 0; nt < 4; nt++)
#pragma unroll
      for (int r = 0; r < 4; r++)
        Ps[wave][(quad * 4 + r) * 72 + nt * 16 + l15] = (__bf16)sc[nt][r];

#pragma unroll
    for (int c = 0; c < 2; c++) {
      bf16x8 af = *(const bf16x8*)&Ps[wave][l15 * 72 + c * 32 + quad * 8];
#pragma unroll
      for (int nt = 0; nt < 4; nt++)
        oacc[nt] = __builtin_amdgcn_mfma_f32_16x16x32_bf16(af, vb[nt][c], oacc[nt], 0, 0, 0);
    }
  }

  // epilogue: O /= l, write bf16 attn-out in (b,s,h*64+d) layout
#pragma unroll
  for (int r = 0; r < 4; r++) {
    const float inv = 1.0f / l_i[r];
    const int row = qr0 + quad * 4 + r;
#pragma unroll
    for (int nt = 0; nt < 4; nt++) {
      float v = oacc[nt][r] * inv;
      aout[(long)(b * Sq + row) * Eq + h * 64 + nt * 16 + l15] = (__bf16)v;
    }
  }
}

// ---------------- launch ----------------
extern "C" void kernel_launch(void* const* d_in, const int* in_sizes, int n_in,
                              void* d_out, int out_size, void* d_ws, size_t ws_size,
                              hipStream_t stream) {
  const float* x      = (const float*)d_in[0];
  const float* w_qkv  = (const float*)d_in[1];
  const float* w_proj = (const float*)d_in[2];
  const float* b_proj = (const float*)d_in[3];
  float* out = (float*)d_out;

  char* w = (char*)d_ws;
  __bf16* xb     = (__bf16*)w; w += (size_t)Mq * Kq * 2;        // 16.8 MB
  __bf16* wqkvb  = (__bf16*)w; w += (size_t)N1q * Kq * 2;       //  6.3 MB
  __bf16* wprojb = (__bf16*)w; w += (size_t)Eq * Kq * 2;        //  2.1 MB
  __bf16* qkvb   = (__bf16*)w; w += (size_t)Mq * N1q * 2;       // 50.3 MB
  __bf16* vtb    = (__bf16*)w; w += (size_t)Bq * Hq * HDq * Sq * 2; // 16.8 MB
  __bf16* attnb  = (__bf16*)w;                                   // 16.8 MB

  cvt4<<<(Mq * Kq / 4 + 255) / 256, 256, 0, stream>>>(x, xb, Mq * Kq / 4);
  cvt4<<<(N1q * Kq / 4 + 255) / 256, 256, 0, stream>>>(w_qkv, wqkvb, N1q * Kq / 4);
  cvt4<<<(Eq * Kq / 4 + 255) / 256, 256, 0, stream>>>(w_proj, wprojb, Eq * Kq / 4);

  gemm_bt<0><<<dim3(Mq / 128, N1q / 128), 256, 0, stream>>>(xb, wqkvb, N1q, Kq, qkvb, nullptr, nullptr);

  transv<<<Bq * Hq * (Sq / 64), 256, 0, stream>>>(qkvb, vtb);

  attn_fwd<<<Bq * Hq * (Sq / 64), 256, 0, stream>>>(qkvb, vtb, attnb);

  gemm_bt<1><<<dim3(Mq / 128, Eq / 128), 256, 0, stream>>>(attnb, wprojb, Eq, Kq, nullptr, b_proj, out);
}

// Round 3
// 292.552 us; speedup vs baseline: 2.2072x; 2.2072x over previous
//
#include <hip/hip_runtime.h>

// ---- problem constants ----
#define Bq   4
#define Sq   2048
#define Eq   1024
#define Hq   16
#define HDq  64
#define Mq   (Bq*Sq)       // 8192
#define N1q  (3*Eq)        // 3072
#define Kq   Eq            // 1024

typedef __bf16 bf16x8 __attribute__((ext_vector_type(8)));
typedef __bf16 bf16x4 __attribute__((ext_vector_type(4)));
typedef float  f32x4  __attribute__((ext_vector_type(4)));
typedef float  f32x16 __attribute__((ext_vector_type(16)));

#define GAS __attribute__((address_space(1)))
#define LAS __attribute__((address_space(3)))

__device__ __forceinline__ void gl2lds16(const void* g, void* l) {
  // async global->LDS, 16B per lane; LDS dest = wave-uniform base + lane*16
  __builtin_amdgcn_global_load_lds((GAS const void*)g, (LAS void*)l, 16, 0, 0);
}

__device__ __forceinline__ unsigned pack2(float a, float b) {
  union { __bf16 h[2]; unsigned u; } x;
  x.h[0] = (__bf16)a; x.h[1] = (__bf16)b; return x.u;
}

// ---------------- fp32 -> bf16 convert (float4 vectorized) ----------------
__global__ __launch_bounds__(256) void cvt4(const float* __restrict__ in,
                                            __bf16* __restrict__ out, int n4) {
  int i = blockIdx.x * 256 + threadIdx.x;
  if (i >= n4) return;
  float4 v = ((const float4*)in)[i];
  bf16x4 o = { (__bf16)v.x, (__bf16)v.y, (__bf16)v.z, (__bf16)v.w };
  ((bf16x4*)out)[i] = o;
}

// ---------------- GEMM  C = A(MxK) * B(NxK)^T  (both K-major, bf16) ------
template <int MODE>
__global__ __launch_bounds__(256) void gemm_bt(const __bf16* __restrict__ A,
                                               const __bf16* __restrict__ Bw,
                                               int N, int K,
                                               __bf16* __restrict__ cbf,
                                               const float* __restrict__ bias,
                                               float* __restrict__ cf32) {
  __shared__ __align__(16) __bf16 As[128 * 32];
  __shared__ __align__(16) __bf16 Bs[128 * 32];
  const int tid  = threadIdx.x;
  const int wave = tid >> 6, lane = tid & 63;
  const int quad = lane >> 4, l15 = lane & 15;
  const int wm = wave & 1, wn = wave >> 1;
  const int bm0 = blockIdx.x * 128;
  const int bn0 = blockIdx.y * 128;

  f32x4 acc[4][4] = {};

  const int ar = tid >> 2, ac = (tid & 3) * 8;
  const __bf16* Ag0 = A  + (long)(bm0 + ar) * K + ac;
  const __bf16* Bg0 = Bw + (long)(bn0 + ar) * K + ac;
  __bf16* As0 = As + wave * 512; __bf16* As1 = As + 2048 + wave * 512;
  __bf16* Bs0 = Bs + wave * 512; __bf16* Bs1 = Bs + 2048 + wave * 512;

  for (int kc = 0; kc < K; kc += 32) {
    gl2lds16(Ag0 + kc,          As0);
    gl2lds16(Ag0 + 64 * K + kc, As1);
    gl2lds16(Bg0 + kc,          Bs0);
    gl2lds16(Bg0 + 64 * K + kc, Bs1);
    __syncthreads();

    bf16x8 af[4], bfr[4];
#pragma unroll
    for (int mt = 0; mt < 4; mt++)
      af[mt] = *(const bf16x8*)&As[(wm * 64 + mt * 16 + l15) * 32 + quad * 8];
#pragma unroll
    for (int nt = 0; nt < 4; nt++)
      bfr[nt] = *(const bf16x8*)&Bs[(wn * 64 + nt * 16 + l15) * 32 + quad * 8];
#pragma unroll
    for (int mt = 0; mt < 4; mt++)
#pragma unroll
      for (int nt = 0; nt < 4; nt++)
        acc[mt][nt] = __builtin_amdgcn_mfma_f32_16x16x32_bf16(af[mt], bfr[nt], acc[mt][nt], 0, 0, 0);
    __syncthreads();
  }

#pragma unroll
  for (int nt = 0; nt < 4; nt++) {
    const int n = bn0 + wn * 64 + nt * 16 + l15;
    float bv = 0.f;
    if (MODE == 1) bv = bias[n];
#pragma unroll
    for (int mt = 0; mt < 4; mt++) {
      const int mbase = bm0 + wm * 64 + mt * 16 + quad * 4;
#pragma unroll
      for (int r = 0; r < 4; r++) {
        const long m = mbase + r;
        if (MODE == 0) cbf[m * N + n] = (__bf16)acc[mt][nt][r];
        else           cf32[m * N + n] = acc[mt][nt][r] + bv;
      }
    }
  }
}

// ---------------- V transpose: qkv natural layout -> vt[bh][d][s] --------
__global__ __launch_bounds__(256) void transv(const __bf16* __restrict__ qkv,
                                              __bf16* __restrict__ vt) {
  __shared__ __align__(16) __bf16 T[64 * 64];
  const int tid = threadIdx.x, wave = tid >> 6;
  const int bh = blockIdx.x >> 5, st = blockIdx.x & 31;
  const int b = bh >> 4, h = bh & 15;
  const long gbase = (long)(b * Sq + st * 64 + (tid >> 3)) * N1q + h * 192 + 128 + (tid & 7) * 8;
  gl2lds16(qkv + gbase,                  T + wave * 512);
  gl2lds16(qkv + gbase + (long)32 * N1q, T + 2048 + wave * 512);
  __syncthreads();
  const int d = tid >> 2, s4 = (tid & 3) * 16;
  bf16x8 o0, o1;
#pragma unroll
  for (int j = 0; j < 8; j++) o0[j] = T[(s4 + j) * 64 + d];
#pragma unroll
  for (int j = 0; j < 8; j++) o1[j] = T[(s4 + 8 + j) * 64 + d];
  __bf16* dst = vt + (long)(bh * 64 + d) * Sq + st * 64 + s4;
  *(bf16x8*)dst = o0;
  *(bf16x8*)(dst + 8) = o1;
}

// ---------------- flash attention fwd (causal), transposed-scores --------
// Grid 512: blockIdx = p*64 + bh (bh low bits -> per-XCD K/V L2 locality).
// Block processes paired q-tiles {p, 15-p} of 128 rows (uniform 17 k-tiles).
// Wave owns 32 q's. S^T = K*Q^T via 32x32x16 MFMA (A=K from swizzled LDS,
// B=Q in regs). Softmax rows live per-lane (q = lane&31): in-register
// reductions + one shfl_xor(32). P^T -> PV B-operand via 2 packed shfl_xor,
// no LDS round-trip. O^T = V^T * P^T accumulates in regs.
__global__ __launch_bounds__(256, 2) void attn_fwd(const __bf16* __restrict__ qkv,
                                                   const __bf16* __restrict__ vt,
                                                   __bf16* __restrict__ aout) {
  __shared__ __align__(16) __bf16 Ks[128 * 64];   // [kcol][d], 16B chunks XOR-swizzled
  __shared__ __align__(16) __bf16 Vs[64 * 128];   // [d][kcol], XOR-swizzled

  const int tid = threadIdx.x;
  const int w = tid >> 6, lane = tid & 63;
  const int c = lane & 31, h = lane >> 5;
  const int bh = blockIdx.x & 63, p = blockIdx.x >> 6;
  const int b = bh >> 4, head = bh & 15;

  const int krr = lane >> 3, kj = lane & 7;    // K staging: 8 rows x 8 chunks
  const int vrr = lane >> 4, vj = lane & 15;   // V staging: 4 rows x 16 chunks
  constexpr float SC2 = 0.18033688011112042f;  // HD^-0.5 * log2(e)

  for (int which = 0; which < 2; ++which) {
    const int qt = which ? (15 - p) : p;
    const int q_g = qt * 128 + w * 32 + c;     // this lane's q row

    // Q B-frags: n = q (lane&31), k = d = kc2*16 + h*8 + j  (reg-resident)
    bf16x8 qf[4];
    const __bf16* qp = qkv + (long)(b * Sq + q_g) * N1q + head * 192 + h * 8;
#pragma unroll
    for (int kc2 = 0; kc2 < 4; kc2++) qf[kc2] = *(const bf16x8*)(qp + kc2 * 16);

    f32x16 oT[2] = {};                 // O^T: d = nf2*32 + rowoff(reg,h), q = c
    float m_i = -1e30f, l_i = 0.f;

    const int nk = qt + 1;
    for (int kt = 0; kt < nk; kt++) {
      // ---- stage K-tile [128 kcol][64 d] and V^T-tile [64 d][128 kcol] ----
#pragma unroll
      for (int i = 0; i < 4; i++) {
        const int row = w * 32 + i * 8 + krr;
        gl2lds16(qkv + (long)(b * Sq + kt * 128 + row) * N1q + head * 192 + 64
                     + (kj ^ (krr & 7)) * 8,
                 Ks + (w * 32 + i * 8) * 64);
      }
#pragma unroll
      for (int i = 0; i < 4; i++) {
        const int dr = w * 16 + i * 4 + vrr;
        gl2lds16(vt + (long)(bh * 64 + dr) * Sq + kt * 128 + (vj ^ (dr & 7)) * 8,
                 Vs + (w * 16 + i * 4) * 128);
      }
      __syncthreads();

      // ---- S^T = K * Q^T : D[m=kcol][n=q], 4 nf tiles of 32 kcols ----
      f32x16 S[4];
#pragma unroll
      for (int nf = 0; nf < 4; nf++) {
        f32x16 z = {};
#pragma unroll
        for (int kc2 = 0; kc2 < 4; kc2++) {
          bf16x8 kf = *(const bf16x8*)&Ks[(nf * 32 + c) * 64 + (((kc2 * 2 + h) ^ (c & 7)) * 8)];
          z = __builtin_amdgcn_mfma_f32_32x32x16_bf16(kf, qf[kc2], z, 0, 0, 0);
        }
        S[nf] = z;
      }

      // ---- online softmax, per-lane rows (q = c) ----
      float mx = -1e30f;
      if (kt == qt) {
#pragma unroll
        for (int nf = 0; nf < 4; nf++)
#pragma unroll
          for (int r = 0; r < 16; r++) {
            const int kcol = kt * 128 + nf * 32 + (r & 3) + 8 * (r >> 2) + 4 * h;
            float s = S[nf][r] * SC2;
            s = (kcol > q_g) ? -1e30f : s;
            S[nf][r] = s; mx = fmaxf(mx, s);
          }
      } else {
#pragma unroll
        for (int nf = 0; nf < 4; nf++)
#pragma unroll
          for (int r = 0; r < 16; r++) {
            float s = S[nf][r] * SC2;
            S[nf][r] = s; mx = fmaxf(mx, s);
          }
      }
      mx = fmaxf(mx, __shfl_xor(mx, 32));
      const float mn = fmaxf(m_i, mx);
      const float alpha = exp2f(m_i - mn);
      m_i = mn;
      float sum = 0.f;
#pragma unroll
      for (int nf = 0; nf < 4; nf++)
#pragma unroll
        for (int r = 0; r < 16; r++) {
          float pv = exp2f(S[nf][r] - mn);
          S[nf][r] = pv; sum += pv;
        }
      sum += __shfl_xor(sum, 32);
      l_i = l_i * alpha + sum;
      oT[0] *= alpha; oT[1] *= alpha;

      // ---- O^T += V^T * P^T : P^T B-frag built via packed shfl_xor(32) ----
      // B-frag(kc): element j: src reg = (j&3) + 4*(2*(kc&1) + h_b),
      //             src half = (j>>2)&1  -> own/partner select.
#pragma unroll
      for (int kc = 0; kc < 8; kc++) {
        const int nf = kc >> 1, base = 8 * (kc & 1);
        const unsigned pa0 = pack2(S[nf][base + 0], S[nf][base + 1]);
        const unsigned pa1 = pack2(S[nf][base + 2], S[nf][base + 3]);
        const unsigned pb0 = pack2(S[nf][base + 4], S[nf][base + 5]);
        const unsigned pb1 = pack2(S[nf][base + 6], S[nf][base + 7]);
        const unsigned ou0 = h ? pb0 : pa0, ou1 = h ? pb1 : pa1;
        const unsigned su0 = h ? pa0 : pb0, su1 = h ? pa1 : pb1;
        const unsigned ru0 = __shfl_xor(su0, 32), ru1 = __shfl_xor(su1, 32);
        union { bf16x8 v; unsigned u[4]; } pf;
        pf.u[0] = h ? ru0 : ou0;
        pf.u[1] = h ? ru1 : ou1;
        pf.u[2] = h ? ou0 : ru0;
        pf.u[3] = h ? ou1 : ru1;
#pragma unroll
        for (int nf2 = 0; nf2 < 2; nf2++) {
          bf16x8 vf = *(const bf16x8*)&Vs[(nf2 * 32 + c) * 128 + (((kc * 2 + h) ^ (c & 7)) * 8)];
          oT[nf2] = __builtin_amdgcn_mfma_f32_32x32x16_bf16(vf, pf.v, oT[nf2], 0, 0, 0);
        }
      }
      __syncthreads();
    }

    // ---- epilogue: O^T C-layout -> attnb[(b,s),(h*64+d)], 8B packed ----
    const float inv = 1.0f / l_i;
    const long obase = (long)(b * Sq + q_g) * Eq + head * 64;
#pragma unroll
    for (int nf2 = 0; nf2 < 2; nf2++)
#pragma unroll
      for (int g = 0; g < 4; g++) {
        bf16x4 o;
#pragma unroll
        for (int t = 0; t < 4; t++) o[t] = (__bf16)(oT[nf2][g * 4 + t] * inv);
        *(bf16x4*)(aout + obase + nf2 * 32 + 8 * g + 4 * h) = o;
      }
  }
}

// ---------------- launch ----------------
extern "C" void kernel_launch(void* const* d_in, const int* in_sizes, int n_in,
                              void* d_out, int out_size, void* d_ws, size_t ws_size,
                              hipStream_t stream) {
  const float* x      = (const float*)d_in[0];
  const float* w_qkv  = (const float*)d_in[1];
  const float* w_proj = (const float*)d_in[2];
  const float* b_proj = (const float*)d_in[3];
  float* out = (float*)d_out;

  char* w = (char*)d_ws;
  __bf16* xb     = (__bf16*)w; w += (size_t)Mq * Kq * 2;
  __bf16* wqkvb  = (__bf16*)w; w += (size_t)N1q * Kq * 2;
  __bf16* wprojb = (__bf16*)w; w += (size_t)Eq * Kq * 2;
  __bf16* qkvb   = (__bf16*)w; w += (size_t)Mq * N1q * 2;
  __bf16* vtb    = (__bf16*)w; w += (size_t)Bq * Hq * HDq * Sq * 2;
  __bf16* attnb  = (__bf16*)w;

  cvt4<<<(Mq * Kq / 4 + 255) / 256, 256, 0, stream>>>(x, xb, Mq * Kq / 4);
  cvt4<<<(N1q * Kq / 4 + 255) / 256, 256, 0, stream>>>(w_qkv, wqkvb, N1q * Kq / 4);
  cvt4<<<(Eq * Kq / 4 + 255) / 256, 256, 0, stream>>>(w_proj, wprojb, Eq * Kq / 4);

  gemm_bt<0><<<dim3(Mq / 128, N1q / 128), 256, 0, stream>>>(xb, wqkvb, N1q, Kq, qkvb, nullptr, nullptr);

  transv<<<Bq * Hq * (Sq / 64), 256, 0, stream>>>(qkvb, vtb);

  attn_fwd<<<64 * 8, 256, 0, stream>>>(qkvb, vtb, attnb);

  gemm_bt<1><<<dim3(Mq / 128, Eq / 128), 256, 0, stream>>>(attnb, wprojb, Eq, Kq, nullptr, b_proj, out);
}